// Round 9
// baseline (497.903 us; speedup 1.0000x reference)
//
#include <hip/hip_runtime.h>
#include <stdint.h>

// ---------------------------------------------------------------------------
// LLaMA attention block on gfx950. FP32 I/O, bf16 MFMA compute, fp32 accum.
// R14 = R13 resubmitted (R8 bench was an infra failure: container acquisition
// died twice; no kernel result). Changes vs R12:
//   - revert T1 swizzle (R12: doubled FETCH, zero time delta -> qkv is
//     schedule-bound, default dispatch already L2-friendly)
//   - qkv K-loop deepened to m201 flight depth: two counted waits per tile
//     {vmcnt(8) @ph2, vmcnt(6) @ph4} instead of one vmcnt(4) drain.
//   - W_o = R9 2-phase (best-known). flash/cvt unchanged.
// ---------------------------------------------------------------------------

typedef __bf16 bf16_t;
typedef __bf16 bf16x8 __attribute__((ext_vector_type(8)));
typedef float  f32x4  __attribute__((ext_vector_type(4)));

#define SEQ    2048
#define DIM    4096
#define NHEADS 32
#define NKV    8
#define HD     128
#define KVDIM  (NKV * HD)  // 1024
#define ATTN_SCALE 0.08838834764831845f  // 1/sqrt(128)

// direct global->LDS, 16B/lane; LDS dest must be wave-uniform base + lane*16.
__device__ __forceinline__ void gld_lds16(const bf16_t* g, bf16_t* l) {
  __builtin_amdgcn_global_load_lds(
      (const __attribute__((address_space(1))) void*)g,
      (__attribute__((address_space(3))) void*)l, 16, 0, 0);
}

__device__ __forceinline__ bf16x8 load8(const float* p) {
  f32x4 a = *(const f32x4*)p;
  f32x4 b = *(const f32x4*)(p + 4);
  bf16x8 r;
#pragma unroll
  for (int i = 0; i < 4; ++i) { r[i] = (bf16_t)a[i]; r[i + 4] = (bf16_t)b[i]; }
  return r;
}
__device__ __forceinline__ bf16x8 load8(const bf16_t* p) { return *(const bf16x8*)p; }

// ---------------------------------------------------------------------------
// batched fp32 -> bf16, 5 regions; uniform per-region grid-stride loops.
// ---------------------------------------------------------------------------
struct CvtJob { const float* src; bf16_t* dst; int n8; };

__global__ __launch_bounds__(256) void to_bf16_multi(CvtJob j0, CvtJob j1, CvtJob j2,
                                                     CvtJob j3, CvtJob j4, int total8) {
  const int stride = gridDim.x * 256;
  const int tid = blockIdx.x * 256 + threadIdx.x;
#define CVT1(J) do { \
    const float* __restrict__ s_ = (J).src; \
    bf16_t* __restrict__ d_ = (J).dst; \
    const int n_ = (J).n8; \
    for (int i_ = tid; i_ < n_; i_ += stride) { \
      const float* p_ = s_ + (size_t)i_ * 8; \
      f32x4 a_ = *(const f32x4*)p_, b_ = *(const f32x4*)(p_ + 4); \
      bf16x8 r_; \
      _Pragma("unroll") \
      for (int q_ = 0; q_ < 4; ++q_) { r_[q_] = (bf16_t)a_[q_]; r_[q_ + 4] = (bf16_t)b_[q_]; } \
      *(bf16x8*)(d_ + (size_t)i_ * 8) = r_; \
    } \
  } while (0)
  CVT1(j0); CVT1(j1); CVT1(j2); CVT1(j3); CVT1(j4);
#undef CVT1
}

// ---------------------------------------------------------------------------
// 256x256 tile, BK=64, 8 waves (2Mx4N), 512 threads, 128 KiB LDS.
// 4-phase schedule. R13 wait discipline (flight depth 6-8, m201-class):
//   issue order: A(t+1)h0 @ph1, A(t+1)h1 @ph2, B(t+2)h0 @ph3, B(t+2)h1 @ph4.
//   reads:       A(t)h0+B(t)h0 @ph1, B(t)h1 @ph2, A(t)h1 @ph3.
//   waits:       end-ph2 vmcnt(8)  [queue = Ath1,B+1h0,B+1h1,A+1h0,A+1h1 = 10
//                                   -> lands exactly A(t)h1 for ph3]
//                end-ph4 vmcnt(6)  [queue = 12 -> lands B+1h0,B+1h1,A+1h0
//                                   for next tile's ph1/ph2; leaves
//                                   A+1h1,B+2h0,B+2h1 flying]
//   Steady-state invariant at tile start: outstanding = {A(t)h1, B(t+1)x2}.
//   Tail: sA/sB false -> vmcnt(0) drains.
// ---------------------------------------------------------------------------
__device__ __forceinline__ void gemm256_loop(
    const bf16_t* __restrict__ gAt, const bf16_t* __restrict__ gBt,
    bf16_t* __restrict__ lAt, bf16_t* __restrict__ lBt,
    const bf16_t* __restrict__ rA, const bf16_t* __restrict__ rB,
    int swz0, int swz1, int Kst, int Klen, f32x4 (&acc)[2][4][2][2]) {
  const int NT = Klen >> 6;  // K-tiles of 64; requires NT >= 4
  bf16x8 af[4][2];           // A frags for current m-half (overwritten ph1/ph3)
  bf16x8 bfr[2][2][2];       // B frags, both n-halves retained across the tile

#define G8_STA(b, h, kt) do { \
    gld_lds16(gAt + (size_t)((h) * 128) * Kst + (size_t)(kt) * 64, \
              lAt + (b) * 16384 + (h) * 8192); \
    gld_lds16(gAt + (size_t)((h) * 128 + 64) * Kst + (size_t)(kt) * 64, \
              lAt + (b) * 16384 + (h) * 8192 + 4096); \
  } while (0)
#define G8_STB(b, h, kt) do { \
    gld_lds16(gBt + (size_t)((h) * 128) * Kst + (size_t)(kt) * 64, \
              lBt + (b) * 16384 + (h) * 8192); \
    gld_lds16(gBt + (size_t)((h) * 128 + 64) * Kst + (size_t)(kt) * 64, \
              lBt + (b) * 16384 + (h) * 8192 + 4096); \
  } while (0)
#define G8_RDA(b, mh) do { \
    _Pragma("unroll") \
    for (int mt = 0; mt < 4; ++mt) { \
      const bf16_t* p_ = rA + (b) * 16384 + ((mh) * 64 + mt * 16) * 64; \
      af[mt][0] = *(const bf16x8*)(p_ + swz0); \
      af[mt][1] = *(const bf16x8*)(p_ + swz1); \
    } \
  } while (0)
#define G8_RDB(b, nh) do { \
    _Pragma("unroll") \
    for (int n2 = 0; n2 < 2; ++n2) { \
      const bf16_t* p_ = rB + (b) * 16384 + ((nh) * 32 + n2 * 16) * 64; \
      bfr[nh][n2][0] = *(const bf16x8*)(p_ + swz0); \
      bfr[nh][n2][1] = *(const bf16x8*)(p_ + swz1); \
    } \
  } while (0)
#define G8_MM(mh, nh) do { \
    _Pragma("unroll") \
    for (int mt = 0; mt < 4; ++mt) \
      _Pragma("unroll") \
      for (int n2 = 0; n2 < 2; ++n2) \
        _Pragma("unroll") \
        for (int ks = 0; ks < 2; ++ks) \
          acc[mh][mt][nh][n2] = __builtin_amdgcn_mfma_f32_16x16x32_bf16( \
              af[mt][ks], bfr[nh][n2][ks], acc[mh][mt][nh][n2], 0, 0, 0); \
  } while (0)
#define G8_BAR()   __builtin_amdgcn_s_barrier()
#define G8_SB()    __builtin_amdgcn_sched_barrier(0)
#define G8_LGKM0() asm volatile("s_waitcnt lgkmcnt(0)" ::: "memory")

  // prologue: tile0 fully + B-halves of tile1; vmcnt(4) lands tile0,
  // leaves B1 flying (4 loads).
  G8_STA(0, 0, 0); G8_STA(0, 1, 0); G8_STB(0, 0, 0); G8_STB(0, 1, 0);
  G8_STB(1, 0, 1); G8_STB(1, 1, 1);
  asm volatile("s_waitcnt vmcnt(4)" ::: "memory");
  G8_BAR(); G8_SB();

  for (int t = 0; t < NT; ++t) {
    const int  b  = t & 1, ob = b ^ 1;
    const bool sA = (t + 1 < NT);
    const bool sB = (t + 2 < NT);

    // ---- phase 1: mh0 x nh0 (12 ds_reads -> early partial drain)
    G8_RDA(b, 0);
    G8_RDB(b, 0);
    if (sA) G8_STA(ob, 0, t + 1);
    asm volatile("s_waitcnt lgkmcnt(8)" ::: "memory");
    G8_BAR(); G8_LGKM0(); G8_SB();
    __builtin_amdgcn_s_setprio(1); G8_MM(0, 0); __builtin_amdgcn_s_setprio(0);
    G8_BAR(); G8_SB();

    // ---- phase 2: mh0 x nh1 (+ counted vmcnt: land A(t)h1 for ph3 only)
    G8_RDB(b, 1);
    if (sA) G8_STA(ob, 1, t + 1);
    G8_BAR(); G8_LGKM0(); G8_SB();
    __builtin_amdgcn_s_setprio(1); G8_MM(0, 1); __builtin_amdgcn_s_setprio(0);
    if (sA) { asm volatile("s_waitcnt vmcnt(8)" ::: "memory"); }
    else    { asm volatile("s_waitcnt vmcnt(0)" ::: "memory"); }
    G8_BAR(); G8_SB();

    // ---- phase 3: mh1 x nh0
    G8_RDA(b, 1);
    if (sB) G8_STB(b, 0, t + 2);
    G8_BAR(); G8_LGKM0(); G8_SB();
    __builtin_amdgcn_s_setprio(1); G8_MM(1, 0); __builtin_amdgcn_s_setprio(0);
    G8_BAR(); G8_SB();

    // ---- phase 4: mh1 x nh1 (+ counted vmcnt(6): next tile's ph1/ph2
    //      inputs land; A(t+1)h1 + B(t+2) stay in flight)
    if (sB) G8_STB(b, 1, t + 2);
    G8_BAR(); G8_SB();
    __builtin_amdgcn_s_setprio(1); G8_MM(1, 1); __builtin_amdgcn_s_setprio(0);
    if (sB) { asm volatile("s_waitcnt vmcnt(6)" ::: "memory"); }
    else    { asm volatile("s_waitcnt vmcnt(0)" ::: "memory"); }
    G8_BAR(); G8_SB();
  }

#undef G8_STA
#undef G8_STB
#undef G8_RDA
#undef G8_RDB
#undef G8_MM
#undef G8_BAR
#undef G8_SB
#undef G8_LGKM0
}

// per-thread setup shared by the 4-phase-family kernels
struct G8Idx {
  int wr, wc, l16, quad, rowl, colL, colS, swz0, swz1;
};
__device__ __forceinline__ G8Idx g8_idx() {
  G8Idx g;
  const int t = threadIdx.x;
  const int w = t >> 6, lane = t & 63;
  g.wr   = w >> 2;            // m-half of the 256-row tile (0..1)
  g.wc   = w & 3;             // col quarter (0..3)
  g.l16  = lane & 15;
  g.quad = lane >> 4;
  g.rowl = w * 8 + (lane >> 3);                 // staging row within 64-row call
  g.colL = (lane & 7) * 8;                      // linear LDS chunk
  g.colS = ((lane & 7) ^ (lane >> 3)) * 8;      // pre-swizzled global chunk
  g.swz0 = ((g.quad ^ (g.l16 & 7)) * 8);        // read-side XOR, ks=0
  g.swz1 = (((4 + g.quad) ^ (g.l16 & 7)) * 8);  // read-side XOR, ks=1
  return g;
}

// ---------------------------------------------------------------------------
// Fused QKV projection + RoPE + 1/sqrt(d) Q-scale + V^T store (4-phase 256²).
// Grid (24, 8): blockIdx.x tiles of 256 over [Q(0..15) | K(16..19) | V(20..23)]
// ---------------------------------------------------------------------------
__global__ __launch_bounds__(512) void gemm8_qkv(const bf16_t* __restrict__ A,
                                                 const bf16_t* __restrict__ Bq,
                                                 const bf16_t* __restrict__ Bk,
                                                 const bf16_t* __restrict__ Bv,
                                                 bf16_t* __restrict__ Qw,
                                                 bf16_t* __restrict__ Kw,
                                                 bf16_t* __restrict__ Vw,
                                                 const float* __restrict__ fcos,
                                                 const float* __restrict__ fsin) {
  __shared__ __align__(16) bf16_t As[32768];  // 2 buf x 2 half x 128x64
  __shared__ __align__(16) bf16_t Bs[32768];

  const G8Idx g = g8_idx();
  const int tm = blockIdx.y * 256;
  const int tn = blockIdx.x * 256;
  const int K  = DIM;

  const int region = (tn >= DIM + KVDIM) ? 2 : (tn >= DIM ? 1 : 0);
  const bf16_t* Bsel;
  int bn;
  if (region == 0)      { Bsel = Bq; bn = tn; }
  else if (region == 1) { Bsel = Bk; bn = tn - DIM; }
  else                  { Bsel = Bv; bn = tn - DIM - KVDIM; }

  const bf16_t* gAt = A + (size_t)(tm + g.rowl) * K + g.colS;
  const bf16_t* gBt = Bsel + (size_t)(bn + g.rowl) * K + g.colS;
  bf16_t* lAt = As + g.rowl * 64 + g.colL;
  bf16_t* lBt = Bs + g.rowl * 64 + g.colL;
  const bf16_t* rA = As + g.wr * 8192 + g.l16 * 64;
  const bf16_t* rB = Bs + (g.wc >> 1) * 8192 + ((g.wc & 1) * 64 + g.l16) * 64;

  f32x4 acc[2][4][2][2] = {};
  gemm256_loop(gAt, gBt, lAt, lBt, rA, rB, g.swz0, g.swz1, K, K, acc);

  // epilogue. C/D frag layout: col = l16, row = quad*4 + r.
  if (region == 2) {
    // V: transposed store Vw[d][s]
#pragma unroll
    for (int mh = 0; mh < 2; ++mh)
#pragma unroll
      for (int mt = 0; mt < 4; ++mt)
#pragma unroll
        for (int nh = 0; nh < 2; ++nh)
#pragma unroll
          for (int n2 = 0; n2 < 2; ++n2) {
            const int row = tm + g.wr * 128 + mh * 64 + mt * 16 + g.quad * 4;
            const int col = bn + g.wc * 64 + nh * 32 + n2 * 16 + g.l16;
#pragma unroll
            for (int r = 0; r < 4; ++r)
              Vw[(size_t)col * SEQ + row + r] = (bf16_t)acc[mh][mt][nh][n2][r];
          }
  } else {
    // Q or K: RoPE via lane^1 partner exchange; Q additionally scaled.
    const float sc   = (region == 0) ? ATTN_SCALE : 1.0f;
    const bool  even = ((g.l16 & 1) == 0);
#pragma unroll
    for (int mh = 0; mh < 2; ++mh)
#pragma unroll
      for (int mt = 0; mt < 4; ++mt)
#pragma unroll
        for (int nh = 0; nh < 2; ++nh)
#pragma unroll
          for (int n2 = 0; n2 < 2; ++n2) {
            const int col = bn + g.wc * 64 + nh * 32 + n2 * 16 + g.l16;
            const int j   = (col & 127) >> 1;
#pragma unroll
            for (int r = 0; r < 4; ++r) {
              const int row = tm + g.wr * 128 + mh * 64 + mt * 16 + g.quad * 4 + r;
              const float v  = acc[mh][mt][nh][n2][r];
              const float p  = __shfl_xor(v, 1, 64);
              const float c  = fcos[row * 64 + j];
              const float sn = fsin[row * 64 + j];
              const float o  = sc * (even ? (v * c - p * sn) : (p * sn + v * c));
              if (region == 0) Qw[(size_t)row * DIM + col]   = (bf16_t)o;
              else             Kw[(size_t)row * KVDIM + col] = (bf16_t)o;
            }
          }
  }
}

// ---------------------------------------------------------------------------
// R9-proven single-pass W_o GEMM, 256x128 tile, BK=64, 8 waves (2Mx4N of 32
// cols), 512 threads, 96 KiB LDS, grid (N/128, M/256) = 256 blocks = 1/CU.
// 2 phases/K-tile, counted vmcnt(2). (No swizzle: R12 refuted T1 here.)
// ---------------------------------------------------------------------------
__global__ __launch_bounds__(512) void gemm8_no(const bf16_t* __restrict__ A,
                                                const bf16_t* __restrict__ B,
                                                float* __restrict__ C,
                                                int M, int N, int K) {
  __shared__ __align__(16) bf16_t As[32768];  // 2 buf x 2 half x 128x64 (64 KiB)
  __shared__ __align__(16) bf16_t Bs[16384];  // 2 buf x 128x64 (32 KiB)

  const G8Idx g = g8_idx();
  const int tm = blockIdx.y * 256;
  const int tn = blockIdx.x * 128;
  const int NT = K >> 6;

  const bf16_t* gAt = A + (size_t)(tm + g.rowl) * K + g.colS;
  const bf16_t* gBt = B + (size_t)(tn + g.rowl) * K + g.colS;
  bf16_t* lAt = As + g.rowl * 64 + g.colL;
  bf16_t* lBt = Bs + g.rowl * 64 + g.colL;
  const bf16_t* rA = As + g.wr * 8192 + g.l16 * 64;
  const bf16_t* rB = Bs + (g.wc * 32 + g.l16) * 64;

  f32x4 acc[2][4][2] = {};
  bf16x8 af[4][2];
  bf16x8 bfr[2][2];  // n2 x ks

#define N1_STA(b, h, kt) do { \
    gld_lds16(gAt + (size_t)((h) * 128) * K + (size_t)(kt) * 64, \
              lAt + (b) * 16384 + (h) * 8192); \
    gld_lds16(gAt + (size_t)((h) * 128 + 64) * K + (size_t)(kt) * 64, \
              lAt + (b) * 16384 + (h) * 8192 + 4096); \
  } while (0)
#define N1_STB(b, kt) do { \
    gld_lds16(gBt + (size_t)(kt) * 64, lBt + (b) * 8192); \
    gld_lds16(gBt + (size_t)64 * K + (size_t)(kt) * 64, lBt + (b) * 8192 + 4096); \
  } while (0)
#define N1_RDA(b, mh) do { \
    _Pragma("unroll") \
    for (int mt = 0; mt < 4; ++mt) { \
      const bf16_t* p_ = rA + (b) * 16384 + ((mh) * 64 + mt * 16) * 64; \
      af[mt][0] = *(const bf16x8*)(p_ + g.swz0); \
      af[mt][1] = *(const bf16x8*)(p_ + g.swz1); \
    } \
  } while (0)
#define N1_RDB(b) do { \
    _Pragma("unroll") \
    for (int n2 = 0; n2 < 2; ++n2) { \
      const bf16_t* p_ = rB + (b) * 8192 + (n2 * 16) * 64; \
      bfr[n2][0] = *(const bf16x8*)(p_ + g.swz0); \
      bfr[n2][1] = *(const bf16x8*)(p_ + g.swz1); \
    } \
  } while (0)
#define N1_MM(mh) do { \
    _Pragma("unroll") \
    for (int mt = 0; mt < 4; ++mt) \
      _Pragma("unroll") \
      for (int n2 = 0; n2 < 2; ++n2) \
        _Pragma("unroll") \
        for (int ks = 0; ks < 2; ++ks) \
          acc[mh][mt][n2] = __builtin_amdgcn_mfma_f32_16x16x32_bf16( \
              af[mt][ks], bfr[n2][ks], acc[mh][mt][n2], 0, 0, 0); \
  } while (0)
#define N1_BAR()   __builtin_amdgcn_s_barrier()
#define N1_SB()    __builtin_amdgcn_sched_barrier(0)
#define N1_LGKM0() asm volatile("s_waitcnt lgkmcnt(0)" ::: "memory")

  // prologue: tile0 A+B, tile1 B (steady-state queue shape)
  N1_STA(0, 0, 0); N1_STA(0, 1, 0); N1_STB(0, 0); N1_STB(1, 1);
  asm volatile("s_waitcnt vmcnt(2)" ::: "memory");  // tile0 landed; t1 B in flight
  N1_BAR(); N1_SB();

  for (int t = 0; t < NT; ++t) {
    const int  b  = t & 1, ob = b ^ 1;
    const bool sA = (t + 1 < NT);
    const bool sB = (t + 2 < NT);

    // ---- phase 1: mh0 (12 ds_reads)
    N1_RDA(b, 0);
    N1_RDB(b);
    if (sA) { N1_STA(ob, 0, t + 1); N1_STA(ob, 1, t + 1); }
    asm volatile("s_waitcnt lgkmcnt(8)" ::: "memory");
    N1_BAR(); N1_LGKM0(); N1_SB();
    __builtin_amdgcn_s_setprio(1); N1_MM(0); __builtin_amdgcn_s_setprio(0);
    N1_BAR(); N1_SB();

    // ---- phase 2: mh1 (+ counted vmcnt, never 0 in steady state)
    N1_RDA(b, 1);
    if (sB) N1_STB(b, t + 2);
    N1_BAR(); N1_LGKM0(); N1_SB();
    __builtin_amdgcn_s_setprio(1); N1_MM(1); __builtin_amdgcn_s_setprio(0);
    if (sB) { asm volatile("s_waitcnt vmcnt(2)" ::: "memory"); }
    else    { asm volatile("s_waitcnt vmcnt(0)" ::: "memory"); }
    N1_BAR(); N1_SB();
  }

#undef N1_STA
#undef N1_STB
#undef N1_RDA
#undef N1_RDB
#undef N1_MM
#undef N1_BAR
#undef N1_SB
#undef N1_LGKM0

  // epilogue: fp32 C
#pragma unroll
  for (int mh = 0; mh < 2; ++mh)
#pragma unroll
    for (int mt = 0; mt < 4; ++mt)
#pragma unroll
      for (int n2 = 0; n2 < 2; ++n2) {
        const int col = tn + g.wc * 32 + n2 * 16 + g.l16;
#pragma unroll
        for (int r = 0; r < 4; ++r) {
          const int row = tm + g.wr * 128 + mh * 64 + mt * 16 + g.quad * 4 + r;
          C[(size_t)row * N + col] = acc[mh][mt][n2][r];
        }
      }
}

// ---------------------------------------------------------------------------
// shared GEMM main loop (R5, 128x128, kept for fallback tiers)
// ---------------------------------------------------------------------------
template <typename TB>
__device__ __forceinline__ void gemm_mainloop(const bf16_t* gA, const TB* gB, int K,
                                              bf16_t* As, bf16_t* Bs,
                                              bf16_t* lA, bf16_t* lB,
                                              int wr, int wc, int l16, int quad,
                                              f32x4 (&acc)[4][4]) {
  for (int kt = 0; kt < K; kt += 64) {
#pragma unroll
    for (int i = 0; i < 4; ++i)
      gld_lds16(gA + (size_t)i * 32 * K + kt, lA + i * 2048);
    if constexpr (sizeof(TB) == 2) {
#pragma unroll
      for (int i = 0; i < 4; ++i)
        gld_lds16((const bf16_t*)gB + (size_t)i * 32 * K + kt, lB + i * 2048);
    } else {
      bf16x8 rb[4];
#pragma unroll
      for (int i = 0; i < 4; ++i) rb[i] = load8(gB + (size_t)i * 32 * K + kt);
#pragma unroll
      for (int i = 0; i < 4; ++i) *(bf16x8*)(lB + i * 2048) = rb[i];
    }
    __syncthreads();

#pragma unroll
    for (int ks = 0; ks < 2; ++ks) {
      bf16x8 af[4], bfr[4];
#pragma unroll
      for (int mt = 0; mt < 4; ++mt)
        af[mt] = *(const bf16x8*)&As[(wr * 64 + mt * 16 + l16) * 64 + ks * 32 + quad * 8];
#pragma unroll
      for (int nt = 0; nt < 4; ++nt)
        bfr[nt] = *(const bf16x8*)&Bs[(wc * 64 + nt * 16 + l16) * 64 + ks * 32 + quad * 8];
#pragma unroll
      for (int mt = 0; mt < 4; ++mt)
#pragma unroll
        for (int nt = 0; nt < 4; ++nt)
          acc[mt][nt] = __builtin_amdgcn_mfma_f32_16x16x32_bf16(af[mt], bfr[nt],
                                                                acc[mt][nt], 0, 0, 0);
    }
    __syncthreads();
  }
}

// ---------------------------------------------------------------------------
// R5 fused QKV (128x128) — fallback tier B (fp32 weights path)
// ---------------------------------------------------------------------------
template <typename TB>
__global__ __launch_bounds__(256) void gemm_qkv(const bf16_t* __restrict__ A,
                                                const TB* __restrict__ Bq,
                                                const TB* __restrict__ Bk,
                                                const TB* __restrict__ Bv,
                                                bf16_t* __restrict__ Qw,
                                                bf16_t* __restrict__ Kw,
                                                bf16_t* __restrict__ Vw,
                                                const float* __restrict__ fcos,
                                                const float* __restrict__ fsin) {
  __shared__ __align__(16) bf16_t As[128 * 64];
  __shared__ __align__(16) bf16_t Bs[128 * 64];

  const int t    = threadIdx.x;
  const int w    = t >> 6;
  const int lane = t & 63;
  const int wr   = w >> 1;
  const int wc   = w & 1;
  const int l16  = lane & 15;
  const int quad = lane >> 4;
  const int tm   = blockIdx.y * 128;
  const int tn   = blockIdx.x * 128;
  const int srow = lane >> 3;
  const int scol = (lane & 7) * 8;
  const int K    = DIM;

  const int region = (tn >= DIM + KVDIM) ? 2 : (tn >= DIM ? 1 : 0);
  const TB* Bsel;
  int bn;
  if (region == 0)      { Bsel = Bq; bn = tn; }
  else if (region == 1) { Bsel = Bk; bn = tn - DIM; }
  else                  { Bsel = Bv; bn = tn - DIM - KVDIM; }

  const bf16_t* gA = A + (size_t)(tm + w * 8 + srow) * K + scol;
  const TB*     gB = Bsel + (size_t)(bn + w * 8 + srow) * K + scol;
  bf16_t* lA = &As[(w * 8 + srow) * 64 + scol];
  bf16_t* lB = &Bs[(w * 8 + srow) * 64 + scol];

  f32x4 acc[4][4] = {};
  gemm_mainloop<TB>(gA, gB, K, As, Bs, lA, lB, wr, wc, l16, quad, acc);

  if (region == 2) {
#pragma unroll
    for (int mt = 0; mt < 4; ++mt)
#pragma unroll
      for (int nt = 0; nt < 4; ++nt) {
        const int row = tm + wr * 64 + mt * 16 + quad * 4;
        const int col = bn + wc * 64 + nt * 16 + l16;
#pragma unroll
        for (int r = 0; r < 4; ++r)
          Vw[(size_t)col * SEQ + row + r] = (bf16_t)acc[mt][nt][r];
      }
  } else {
    const float sc = (region == 0) ? ATTN_SCALE : 1.0f;
    const bool even = ((l16 & 1) == 0);
#pragma unroll
    for (int mt = 0; mt < 4; ++mt)
#pragma unroll
      for (int nt = 0; nt < 4; ++nt) {
        const int col = bn + wc * 64 + nt * 16 + l16;
        const int j   = (col & 127) >> 1;
#pragma unroll
        for (int r = 0; r < 4; ++r) {
          const int row = tm + wr * 64 + mt * 16 + quad * 4 + r;
          const float v = acc[mt][nt][r];
          const float p = __shfl_xor(v, 1, 64);
          const float c  = fcos[row * 64 + j];
          const float sn = fsin[row * 64 + j];
          const float o  = sc * (even ? (v * c - p * sn) : (p * sn + v * c));
          if (region == 0) Qw[(size_t)row * DIM + col]   = (bf16_t)o;
          else             Kw[(size_t)row * KVDIM + col] = (bf16_t)o;
        }
      }
  }
}

// ---------------------------------------------------------------------------
// Plain GEMM (128x128) — fallback tier B
// ---------------------------------------------------------------------------
template <typename TB, typename TC>
__global__ __launch_bounds__(256) void gemm_lds(const bf16_t* __restrict__ A,
                                                const TB* __restrict__ B,
                                                TC* __restrict__ C,
                                                int M, int N, int K) {
  __shared__ __align__(16) bf16_t As[128 * 64];
  __shared__ __align__(16) bf16_t Bs[128 * 64];

  const int t    = threadIdx.x;
  const int w    = t >> 6;
  const int lane = t & 63;
  const int wr   = w >> 1;
  const int wc   = w & 1;
  const int l16  = lane & 15;
  const int quad = lane >> 4;
  const int tm   = blockIdx.y * 128;
  const int tn   = blockIdx.x * 128;
  const int srow = lane >> 3;
  const int scol = (lane & 7) * 8;

  const bf16_t* gA = A + (size_t)(tm + w * 8 + srow) * K + scol;
  const TB*     gB = B + (size_t)(tn + w * 8 + srow) * K + scol;
  bf16_t* lA = &As[(w * 8 + srow) * 64 + scol];
  bf16_t* lB = &Bs[(w * 8 + srow) * 64 + scol];

  f32x4 acc[4][4] = {};
  gemm_mainloop<TB>(gA, gB, K, As, Bs, lA, lB, wr, wc, l16, quad, acc);

#pragma unroll
  for (int mt = 0; mt < 4; ++mt)
#pragma unroll
    for (int nt = 0; nt < 4; ++nt)
#pragma unroll
      for (int r = 0; r < 4; ++r) {
        const int row = tm + wr * 64 + mt * 16 + quad * 4 + r;
        const int col = tn + wc * 64 + nt * 16 + l16;
        C[(size_t)row * N + col] = (TC)acc[mt][nt][r];
      }
}

// ---------------------------------------------------------------------------
// R3-style register-staging GEMM (fallback tier C)
// ---------------------------------------------------------------------------
template <typename TA, typename TB, typename TC, bool TRANSPOSE_C>
__global__ __launch_bounds__(256) void gemm_reg(const TA* __restrict__ A,
                                                const TB* __restrict__ B,
                                                TC* __restrict__ C,
                                                int M, int N, int K) {
  __shared__ __align__(16) bf16_t As[128 * 64];
  __shared__ __align__(16) bf16_t Bs[128 * 64];

  const int t    = threadIdx.x;
  const int w    = t >> 6;
  const int lane = t & 63;
  const int wr   = w >> 1;
  const int wc   = w & 1;
  const int l16  = lane & 15;
  const int quad = lane >> 4;
  const int tm   = blockIdx.y * 128;
  const int tn   = blockIdx.x * 128;
  const int srow = lane >> 3;
  const int scol = (lane & 7) * 8;

  const TA* gA = A + (size_t)(tm + w * 8 + srow) * K + scol;
  const TB* gB = B + (size_t)(tn + w * 8 + srow) * K + scol;
  bf16_t* lA = &As[(w * 8 + srow) * 64 + scol];
  bf16_t* lB = &Bs[(w * 8 + srow) * 64 + scol];

  f32x4 acc[4][4] = {};

  for (int kt = 0; kt < K; kt += 64) {
    bf16x8 ra[4], rb[4];
#pragma unroll
    for (int i = 0; i < 4; ++i) ra[i] = load8(gA + (size_t)i * 32 * K + kt);
#pragma unroll
    for (int i = 0; i < 4; ++i) rb[i] = load8(gB + (size_t)i * 32 * K + kt);
#pragma unroll
    for (int i = 0; i < 4; ++i) *(bf16x8*)(lA + i * 2048) = ra[i];
#pragma unroll
    for (int i = 0; i < 4; ++i) *(bf16x8*)(lB + i * 2048) = rb[i];
    __syncthreads();

#pragma unroll
    for (int ks = 0; ks < 2; ++ks) {
      bf16x8 af[4], bfr[4];
#pragma unroll
      for (int mt = 0; mt < 4; ++mt)
        af[mt] = *(const bf16x8*)&As[(wr * 64 + mt * 16 + l16) * 64 + ks * 32 + quad * 8];
#pragma unroll
      for (int nt = 0; nt < 4; ++nt)
        bfr[nt] = *(const bf16x8*)&Bs[(wc * 64 + nt * 16 + l16) * 64 + ks * 32 + quad * 8];
#pragma unroll
      for (int mt = 0; mt < 4; ++mt)
#pragma unroll
        for (int nt = 0; nt < 4; ++nt)
          acc[mt][nt] = __builtin_amdgcn_mfma_f32_16x16x32_bf16(af[mt], bfr[nt],
                                                                acc[mt][nt], 0, 0, 0);
    }
    __syncthreads();
  }

  if (!TRANSPOSE_C) {
#pragma unroll
    for (int mt = 0; mt < 4; ++mt)
#pragma unroll
      for (int nt = 0; nt < 4; ++nt)
#pragma unroll
        for (int r = 0; r < 4; ++r) {
          const int row = tm + wr * 64 + mt * 16 + quad * 4 + r;
          const int col = tn + wc * 64 + nt * 16 + l16;
          C[(size_t)row * N + col] = (TC)acc[mt][nt][r];
        }
  } else {
#pragma unroll
    for (int mt = 0; mt < 4; ++mt)
#pragma unroll
      for (int nt = 0; nt < 4; ++nt) {
        const int row = tm + wr * 64 + mt * 16 + quad * 4;
        const int col = tn + wc * 64 + nt * 16 + l16;
#pragma unroll
        for (int r = 0; r < 4; ++r)
          C[(size_t)col * M + row + r] = (TC)acc[mt][nt][r];
      }
  }
}

// ---------------------------------------------------------------------------
// RoPE in place on bf16 T[s][h*128+d] (fallback tiers), post-scale `sc`.
// ---------------------------------------------------------------------------
template <int NH_T>
__global__ __launch_bounds__(256) void rope_kernel(bf16_t* __restrict__ T,
                                                   const float* __restrict__ cosb,
                                                   const float* __restrict__ sinb,
                                                   float sc) {
  const int idx = blockIdx.x * 256 + threadIdx.x;
  if (idx >= SEQ * NH_T * 64) return;
  const int j = idx & 63;
  const int h = (idx >> 6) & (NH_T - 1);
  const int s = idx >> 6 >> (NH_T == 32 ? 5 : 3);
  const float c  = cosb[s * 64 + j];
  const float sn = sinb[s * 64 + j];
  const size_t o = (size_t)s * (NH_T * HD) + h * HD + 2 * j;
  const float re = (float)T[o];
  const float im = (float)T[o + 1];
  T[o]     = (bf16_t)(sc * (re * c - im * sn));
  T[o + 1] = (bf16_t)(sc * (re * sn + im * c));
}

// ---------------------------------------------------------------------------
// Flash attention (causal, GQA 4:1). Q pre-scaled by 1/sqrt(d).
// R8 fused-pair structure: one k-loop per block; paired Q-tiles (qtL,
// qtH=31-qtL) share K/V staging; double-buffered Ks/Vs, T14, T5.
// ---------------------------------------------------------------------------
__global__ __launch_bounds__(256, 2) void flash_attn(const bf16_t* __restrict__ Q,
                                                     const bf16_t* __restrict__ Kc,
                                                     const bf16_t* __restrict__ Vt,
                                                     bf16_t* __restrict__ O) {
  __shared__ __align__(16) bf16_t Ks[2 * 64 * 128];
  __shared__ __align__(16) bf16_t Vs[2 * 128 * 64];
  __shared__ __align__(16) bf16_t Ps[4 * 16 * 72];

  const int t    = threadIdx.x;
  const int w    = t >> 6;
  const int lane = t & 63;
  const int l16  = lane & 15;
  const int quad = lane >> 4;
  const int h    = blockIdx.x;
  const int hk   = h >> 2;
  const int krow = lane >> 4, kcol = (lane & 15) * 8;
  const int vrow = lane >> 3, vcol = (lane & 7) * 8;
  bf16_t* Pw = &Ps[w * 1152];

#define F_LOAD(KT) do { \
    _Pragma("unroll") \
    for (int i = 0; i < 4; ++i) \
      rk[i] = *(const bf16x8*)(Kc + (size_t)((KT) * 64 + (i * 4 + w) * 4 + krow) * KVDIM \
                               + hk * HD + kcol); \
    _Pragma("unroll") \
    for (int i = 0; i < 4; ++i) \
      rv[i] = *(const bf16x8*)(Vt + (size_t)(hk * HD + (i * 4 + w) * 8 + vrow) * SEQ \
                               + (KT) * 64 + vcol); \
  } while (0)
#define F_STORE(KB, VB) do { \
    _Pragma("unroll") \
    for (int i = 0; i < 4; ++i) { \
      const int r = (i * 4 + w) * 4 + krow; \
      *(bf16x8*)&(KB)[r * 128 + ((l16 ^ (r & 15)) * 8)] = rk[i]; \
    } \
    _Pragma("unroll") \
    for (int i = 0; i < 4; ++i) { \
      const int r = (i * 4 + w) * 8 + vrow; \
      *(bf16x8*)&(VB)[r * 64 + (((lane & 7) ^ (r & 7)) * 8)] = rv[i]; \
    } \
  } while (0)

// one half's QK^T -> masked exp -> P staging -> PV accumulate for tile kt
#define F_HALF(QA, OA, LR, QT) do { \
    f32x4 s_acc[4]; \
    __builtin_amdgcn_s_setprio(1); \
    _Pragma("unroll") \
    for (int nt = 0; nt < 4; ++nt) { \
      f32x4 a = {}; \
      _Pragma("unroll") \
      for (int ks = 0; ks < 4; ++ks) { \
        bf16x8 kb = *(const bf16x8*)&KsC[(nt * 16 + l16) * 128 + (((ks * 4 + quad) ^ l16) * 8)]; \
        a = __builtin_amdgcn_mfma_f32_16x16x32_bf16((QA)[ks], kb, a, 0, 0, 0); \
      } \
      s_acc[nt] = a; \
    } \
    __builtin_amdgcn_s_setprio(0); \
    const bool diag_ = (kt == (QT)); \
    _Pragma("unroll") \
    for (int r = 0; r < 4; ++r) { \
      const int grow_rel = w * 16 + quad * 4 + r; \
      _Pragma("unroll") \
      for (int nt = 0; nt < 4; ++nt) { \
        float p = __expf(fminf(s_acc[nt][r], 30.f)); \
        if (diag_ && (nt * 16 + l16) > grow_rel) p = 0.f; \
        (LR)[r] += p; \
        Pw[(quad * 4 + r) * 72 + nt * 16 + l16] = (bf16_t)p; \
      } \
    } \
    bf16x8 pa[2]; \
    _Pragma("unroll") \
    for (int ks = 0; ks < 2; ++ks) \
      pa[ks] = *(const bf16x8*)&Pw[l16 * 72 + ks * 32 + quad * 8]; \
    __builtin_amdgcn_s_setprio(1); \
    _Pragma("unroll") \
    for (int nt8 = 0; nt8 < 8; ++nt8) \
      _Pragma("unroll") \
      for (int ks = 0; ks < 2; ++ks) { \
        bf16x8 vb = *(const bf16x8*)&VsC[(nt8 * 16 + l16) * 64 \
                                         + (((ks * 4 + quad) ^ (l16 & 7)) * 8)]; \
        (OA)[nt8] = __builtin_amdgcn_mfma_f32_16x16x32_bf16(pa[ks], vb, (OA)[nt8], 0, 0, 0); \
      } \
    __builtin_amdgcn_s_setprio(0); \
  } while (0)

  const int qtL = blockIdx.y;       // 0..15
  const int qtH = 31 - qtL;         // 16..31

  bf16x8 qaL[4], qaH[4];
  {
    const int qrowL = qtL * 64 + w * 16 + l16;
    const int qrowH = qtH * 64 + w * 16 + l16;
#pragma unroll
    for (int ks = 0; ks < 4; ++ks) {
      qaL[ks] = *(const bf16x8*)&Q[(size_t)qrowL * DIM + h * HD + ks * 32 + quad * 8];
      qaH[ks] = *(const bf16x8*)&Q[(size_t)qrowH * DIM + h * HD + ks * 32 + quad * 8];
    }
  }

  f32x4 oaL[8] = {}, oaH[8] = {};
  float lrL[4] = {0.f, 0.f, 0.f, 0.f};
  float lrH[4] = {0.f, 0.f, 0.f, 0.f};

  bf16x8 rk[4], rv[4];
  F_LOAD(0);
  F_STORE(Ks, Vs);  // buf0
  __syncthreads();

  for (int kt = 0; kt <= qtH; ++kt) {
    const int cur = kt & 1;
    const bf16_t* KsC = Ks + cur * 8192;
    const bf16_t* VsC = Vs + cur * 8192;
    bf16_t* KsN = Ks + (cur ^ 1) * 8192;
    bf16_t* VsN = Vs + (cur ^ 1) * 8192;
    const bool pf = (kt < qtH);

    if (pf) F_LOAD(kt + 1);  // issue early; lands during compute (T14)

    F_HALF(qaH, oaH, lrH, qtH);
    if (kt <= qtL) F_HALF(qaL, oaL, lrL, qtL);

    if (pf) F_STORE(KsN, VsN);  // write-late into the other buffer
    __syncthreads();
  }

  // epilogue: both halves
#pragma unroll
  for (int r = 0; r < 4; ++r) {
    float rsH = lrH[r], rsL = lrL[r];
#pragma unroll
    for (int off = 1; off < 16; off <<= 1) {
      rsH += __shfl_xor(rsH, off, 64);
      rsL += __shfl_xor(rsL, off, 64);
    }
    lrH[r] = 1.0f / rsH;
    lrL[r] = 1.0f / rsL;
  }
#pragma unroll
  for (int nt8 = 0; nt8 < 8; ++nt8)
#pragma unroll
    for (int r = 0; r < 4; ++r) {
      const int rowH = qtH * 64 + w * 16 + quad * 4 + r;
      const int rowL = qtL * 64 + w * 16 + quad * 4 + r;
      O[(size_t)rowH * DIM + h * HD + nt8 * 16 + l16] = (bf16_t)(oaH[nt8][r] * lrH[r]);
      O[(size_t)rowL * DIM + h * HD + nt8 * 16 + l16] = (bf16_t)(oaL[nt8][r] * lrL[r]);
    }
#undef F_LOAD
#undef F_STORE
#undef F_HALF
}

// ---------------------------------------------------------------------------
extern "C" void kernel_launch(void* const* d_in, const int* in_sizes, int n_in,
                              void* d_out, int out_size, void* d_ws, size_t ws_size,
                              hipStream_t stream) {
  const float* x    = (const float*)d_in[0];
  const float* wq   = (const float*)d_in[1];
  const float* wk   = (const float*)d_in[2];
  const float* wv   = (const float*)d_in[3];
  const float* wo   = (const float*)d_in[4];
  const float* fcos = (const float*)d_in[7];
  const float* fsin = (const float*)d_in[8];
  float* out = (float*)d_out;

  bf16_t* Qw = (bf16_t*)d_out;  // Q scratch in d_out, dead before final GEMM
  bf16_t* ws = (bf16_t*)d_ws;

  const size_t N_X  = (size_t)SEQ * DIM;
  const size_t N_WQ = (size_t)DIM * DIM;
  const size_t N_WK = (size_t)KVDIM * DIM;
  const size_t N_KV = (size_t)SEQ * KVDIM;

  const size_t NEED_A = (N_X + N_WQ + 2 * N_WK + N_WQ + 2 * N_KV + N_X) * 2;  // 120 MiB
  const size_t NEED_B = (N_X + 2 * N_KV + N_X) * 2;                           // 40 MiB

  const dim3 blk(256);

  if (ws_size >= NEED_A) {
    bf16_t* xb  = ws;
    bf16_t* wqb = xb + N_X;
    bf16_t* wkb = wqb + N_WQ;
    bf16_t* wvb = wkb + N_WK;
    bf16_t* wob = wvb + N_WK;
    bf16_t* Kw  = wob + N_WQ;
    bf16_t* Vw  = Kw + N_KV;
    bf16_t* Aw  = Vw + N_KV;

    const int total8 = (int)((N_X + 2 * N_WQ + 2 * N_WK) / 8);
    to_bf16_multi<<<2048, blk, 0, stream>>>(
        CvtJob{x, xb, (int)(N_X / 8)}, CvtJob{wq, wqb, (int)(N_WQ / 8)},
        CvtJob{wk, wkb, (int)(N_WK / 8)}, CvtJob{wv, wvb, (int)(N_WK / 8)},
        CvtJob{wo, wob, (int)(N_WQ / 8)}, total8);

    // 4-phase 256x256 QKV, deepened waits: grid (24, 8) = 192 blocks.
    gemm8_qkv<<<dim3((DIM + 2 * KVDIM) / 256, SEQ / 256), dim3(512), 0, stream>>>(
        xb, wqb, wkb, wvb, Qw, Kw, Vw, fcos, fsin);
    flash_attn<<<dim3(NHEADS, 16), blk, 0, stream>>>(Qw, Kw, Vw, Aw);

    // R9 2-phase W_o: 256x128 tiles, grid 32x8 = 256 blocks.
    gemm8_no<<<dim3(DIM / 128, SEQ / 256), dim3(512), 0, stream>>>(
        Aw, wob, out, SEQ, DIM, DIM);
  } else if (ws_size >= NEED_B) {
    bf16_t* xb = ws;
    bf16_t* Kw = xb + N_X;
    bf16_t* Vw = Kw + N_KV;
    bf16_t* Aw = Vw + N_KV;

    const int total8 = (int)(N_X / 8);
    to_bf16_multi<<<2048, blk, 0, stream>>>(
        CvtJob{x, xb, total8}, CvtJob{x, xb, 0}, CvtJob{x, xb, 0},
        CvtJob{x, xb, 0}, CvtJob{x, xb, 0}, total8);

    gemm_qkv<float><<<dim3(48, SEQ / 128), blk, 0, stream>>>(
        xb, wq, wk, wv, Qw, Kw, Vw, fcos, fsin);
    flash_attn<<<dim3(NHEADS, 16), blk, 0, stream>>>(Qw, Kw, Vw, Aw);
    gemm_lds<float, float>
        <<<dim3(DIM / 128, SEQ / 128), blk, 0, stream>>>(Aw, wo, out, SEQ, DIM, DIM);
  } else {
    // tier C fallback (R3-proven, 24 MiB ws)
    bf16_t* Kw = ws;
    bf16_t* Vw = Kw + N_KV;
    bf16_t* Aw = Vw + N_KV;

    gemm_reg<float, float, bf16_t, false>
        <<<dim3(DIM / 128, SEQ / 128), blk, 0, stream>>>(x, wq, Qw, SEQ, DIM, DIM);
    gemm_reg<float, float, bf16_t, false>
        <<<dim3(KVDIM / 128, SEQ / 128), blk, 0, stream>>>(x, wk, Kw, SEQ, KVDIM, DIM);
    gemm_reg<float, float, bf16_t, true>
        <<<dim3(KVDIM / 128, SEQ / 128), blk, 0, stream>>>(x, wv, Vw, SEQ, KVDIM, DIM);
    rope_kernel<NHEADS><<<SEQ * NHEADS * 64 / 256, blk, 0, stream>>>(Qw, fcos, fsin, ATTN_SCALE);
    rope_kernel<NKV><<<SEQ * NKV * 64 / 256, blk, 0, stream>>>(Kw, fcos, fsin, 1.0f);
    flash_attn<<<dim3(NHEADS, 16), blk, 0, stream>>>(Qw, Kw, Vw, Aw);
    gemm_reg<bf16_t, float, float, false>
        <<<dim3(DIM / 128, SEQ / 128), blk, 0, stream>>>(Aw, wo, out, SEQ, DIM, DIM);
  }
}

// Round 10
// 461.220 us; speedup vs baseline: 1.0795x; 1.0795x over previous
//
#include <hip/hip_runtime.h>
#include <stdint.h>

// ---------------------------------------------------------------------------
// LLaMA attention block on gfx950. FP32 I/O, bf16 MFMA compute, fp32 accum.
// R15: fuse wo fp32->bf16 conversion into the qkv dispatch as 64 converter
//      blocks (bx>=24) that occupy the 64 CUs idle during qkv (192 GEMM
//      blocks on 256 CUs). Safe per R12: qkv compute blocks are insensitive
//      to concurrent HBM traffic. wo removed from upstream cvt kernel.
//      qkv GEMM path / flash / W_o byte-identical to R14 (passed, 497.9).
// ---------------------------------------------------------------------------

typedef __bf16 bf16_t;
typedef __bf16 bf16x8 __attribute__((ext_vector_type(8)));
typedef float  f32x4  __attribute__((ext_vector_type(4)));

#define SEQ    2048
#define DIM    4096
#define NHEADS 32
#define NKV    8
#define HD     128
#define KVDIM  (NKV * HD)  // 1024
#define ATTN_SCALE 0.08838834764831845f  // 1/sqrt(128)

// direct global->LDS, 16B/lane; LDS dest must be wave-uniform base + lane*16.
__device__ __forceinline__ void gld_lds16(const bf16_t* g, bf16_t* l) {
  __builtin_amdgcn_global_load_lds(
      (const __attribute__((address_space(1))) void*)g,
      (__attribute__((address_space(3))) void*)l, 16, 0, 0);
}

__device__ __forceinline__ bf16x8 load8(const float* p) {
  f32x4 a = *(const f32x4*)p;
  f32x4 b = *(const f32x4*)(p + 4);
  bf16x8 r;
#pragma unroll
  for (int i = 0; i < 4; ++i) { r[i] = (bf16_t)a[i]; r[i + 4] = (bf16_t)b[i]; }
  return r;
}
__device__ __forceinline__ bf16x8 load8(const bf16_t* p) { return *(const bf16x8*)p; }

// ---------------------------------------------------------------------------
// batched fp32 -> bf16, 5 regions; uniform per-region grid-stride loops.
// ---------------------------------------------------------------------------
struct CvtJob { const float* src; bf16_t* dst; int n8; };

__global__ __launch_bounds__(256) void to_bf16_multi(CvtJob j0, CvtJob j1, CvtJob j2,
                                                     CvtJob j3, CvtJob j4, int total8) {
  const int stride = gridDim.x * 256;
  const int tid = blockIdx.x * 256 + threadIdx.x;
#define CVT1(J) do { \
    const float* __restrict__ s_ = (J).src; \
    bf16_t* __restrict__ d_ = (J).dst; \
    const int n_ = (J).n8; \
    for (int i_ = tid; i_ < n_; i_ += stride) { \
      const float* p_ = s_ + (size_t)i_ * 8; \
      f32x4 a_ = *(const f32x4*)p_, b_ = *(const f32x4*)(p_ + 4); \
      bf16x8 r_; \
      _Pragma("unroll") \
      for (int q_ = 0; q_ < 4; ++q_) { r_[q_] = (bf16_t)a_[q_]; r_[q_ + 4] = (bf16_t)b_[q_]; } \
      *(bf16x8*)(d_ + (size_t)i_ * 8) = r_; \
    } \
  } while (0)
  CVT1(j0); CVT1(j1); CVT1(j2); CVT1(j3); CVT1(j4);
#undef CVT1
}

// ---------------------------------------------------------------------------
// 256x256 tile, BK=64, 8 waves (2Mx4N), 512 threads, 128 KiB LDS.
// 4-phase schedule, R13/R14 wait discipline (verified null-but-correct).
// ---------------------------------------------------------------------------
__device__ __forceinline__ void gemm256_loop(
    const bf16_t* __restrict__ gAt, const bf16_t* __restrict__ gBt,
    bf16_t* __restrict__ lAt, bf16_t* __restrict__ lBt,
    const bf16_t* __restrict__ rA, const bf16_t* __restrict__ rB,
    int swz0, int swz1, int Kst, int Klen, f32x4 (&acc)[2][4][2][2]) {
  const int NT = Klen >> 6;  // K-tiles of 64; requires NT >= 4
  bf16x8 af[4][2];           // A frags for current m-half (overwritten ph1/ph3)
  bf16x8 bfr[2][2][2];       // B frags, both n-halves retained across the tile

#define G8_STA(b, h, kt) do { \
    gld_lds16(gAt + (size_t)((h) * 128) * Kst + (size_t)(kt) * 64, \
              lAt + (b) * 16384 + (h) * 8192); \
    gld_lds16(gAt + (size_t)((h) * 128 + 64) * Kst + (size_t)(kt) * 64, \
              lAt + (b) * 16384 + (h) * 8192 + 4096); \
  } while (0)
#define G8_STB(b, h, kt) do { \
    gld_lds16(gBt + (size_t)((h) * 128) * Kst + (size_t)(kt) * 64, \
              lBt + (b) * 16384 + (h) * 8192); \
    gld_lds16(gBt + (size_t)((h) * 128 + 64) * Kst + (size_t)(kt) * 64, \
              lBt + (b) * 16384 + (h) * 8192 + 4096); \
  } while (0)
#define G8_RDA(b, mh) do { \
    _Pragma("unroll") \
    for (int mt = 0; mt < 4; ++mt) { \
      const bf16_t* p_ = rA + (b) * 16384 + ((mh) * 64 + mt * 16) * 64; \
      af[mt][0] = *(const bf16x8*)(p_ + swz0); \
      af[mt][1] = *(const bf16x8*)(p_ + swz1); \
    } \
  } while (0)
#define G8_RDB(b, nh) do { \
    _Pragma("unroll") \
    for (int n2 = 0; n2 < 2; ++n2) { \
      const bf16_t* p_ = rB + (b) * 16384 + ((nh) * 32 + n2 * 16) * 64; \
      bfr[nh][n2][0] = *(const bf16x8*)(p_ + swz0); \
      bfr[nh][n2][1] = *(const bf16x8*)(p_ + swz1); \
    } \
  } while (0)
#define G8_MM(mh, nh) do { \
    _Pragma("unroll") \
    for (int mt = 0; mt < 4; ++mt) \
      _Pragma("unroll") \
      for (int n2 = 0; n2 < 2; ++n2) \
        _Pragma("unroll") \
        for (int ks = 0; ks < 2; ++ks) \
          acc[mh][mt][nh][n2] = __builtin_amdgcn_mfma_f32_16x16x32_bf16( \
              af[mt][ks], bfr[nh][n2][ks], acc[mh][mt][nh][n2], 0, 0, 0); \
  } while (0)
#define G8_BAR()   __builtin_amdgcn_s_barrier()
#define G8_SB()    __builtin_amdgcn_sched_barrier(0)
#define G8_LGKM0() asm volatile("s_waitcnt lgkmcnt(0)" ::: "memory")

  // prologue: tile0 fully + B-halves of tile1; vmcnt(4) lands tile0,
  // leaves B1 flying (4 loads).
  G8_STA(0, 0, 0); G8_STA(0, 1, 0); G8_STB(0, 0, 0); G8_STB(0, 1, 0);
  G8_STB(1, 0, 1); G8_STB(1, 1, 1);
  asm volatile("s_waitcnt vmcnt(4)" ::: "memory");
  G8_BAR(); G8_SB();

  for (int t = 0; t < NT; ++t) {
    const int  b  = t & 1, ob = b ^ 1;
    const bool sA = (t + 1 < NT);
    const bool sB = (t + 2 < NT);

    // ---- phase 1: mh0 x nh0 (12 ds_reads -> early partial drain)
    G8_RDA(b, 0);
    G8_RDB(b, 0);
    if (sA) G8_STA(ob, 0, t + 1);
    asm volatile("s_waitcnt lgkmcnt(8)" ::: "memory");
    G8_BAR(); G8_LGKM0(); G8_SB();
    __builtin_amdgcn_s_setprio(1); G8_MM(0, 0); __builtin_amdgcn_s_setprio(0);
    G8_BAR(); G8_SB();

    // ---- phase 2: mh0 x nh1 (+ counted vmcnt: land A(t)h1 for ph3 only)
    G8_RDB(b, 1);
    if (sA) G8_STA(ob, 1, t + 1);
    G8_BAR(); G8_LGKM0(); G8_SB();
    __builtin_amdgcn_s_setprio(1); G8_MM(0, 1); __builtin_amdgcn_s_setprio(0);
    if (sA) { asm volatile("s_waitcnt vmcnt(8)" ::: "memory"); }
    else    { asm volatile("s_waitcnt vmcnt(0)" ::: "memory"); }
    G8_BAR(); G8_SB();

    // ---- phase 3: mh1 x nh0
    G8_RDA(b, 1);
    if (sB) G8_STB(b, 0, t + 2);
    G8_BAR(); G8_LGKM0(); G8_SB();
    __builtin_amdgcn_s_setprio(1); G8_MM(1, 0); __builtin_amdgcn_s_setprio(0);
    G8_BAR(); G8_SB();

    // ---- phase 4: mh1 x nh1 (+ counted vmcnt(6))
    if (sB) G8_STB(b, 1, t + 2);
    G8_BAR(); G8_SB();
    __builtin_amdgcn_s_setprio(1); G8_MM(1, 1); __builtin_amdgcn_s_setprio(0);
    if (sB) { asm volatile("s_waitcnt vmcnt(6)" ::: "memory"); }
    else    { asm volatile("s_waitcnt vmcnt(0)" ::: "memory"); }
    G8_BAR(); G8_SB();
  }

#undef G8_STA
#undef G8_STB
#undef G8_RDA
#undef G8_RDB
#undef G8_MM
#undef G8_BAR
#undef G8_SB
#undef G8_LGKM0
}

// per-thread setup shared by the 4-phase-family kernels
struct G8Idx {
  int wr, wc, l16, quad, rowl, colL, colS, swz0, swz1;
};
__device__ __forceinline__ G8Idx g8_idx() {
  G8Idx g;
  const int t = threadIdx.x;
  const int w = t >> 6, lane = t & 63;
  g.wr   = w >> 2;            // m-half of the 256-row tile (0..1)
  g.wc   = w & 3;             // col quarter (0..3)
  g.l16  = lane & 15;
  g.quad = lane >> 4;
  g.rowl = w * 8 + (lane >> 3);                 // staging row within 64-row call
  g.colL = (lane & 7) * 8;                      // linear LDS chunk
  g.colS = ((lane & 7) ^ (lane >> 3)) * 8;      // pre-swizzled global chunk
  g.swz0 = ((g.quad ^ (g.l16 & 7)) * 8);        // read-side XOR, ks=0
  g.swz1 = (((4 + g.quad) ^ (g.l16 & 7)) * 8);  // read-side XOR, ks=1
  return g;
}

// ---------------------------------------------------------------------------
// Fused QKV projection + RoPE + Q-scale + V^T store (4-phase 256²)
// + R15: wo fp32->bf16 converter blocks.
// Grid (32, 8): bx in [0,24) -> GEMM tiles (192 blocks, 75% of CUs);
//               bx in [24,32) -> 64 converter blocks on the otherwise-idle
//               CUs, grid-striding wo (block-uniform branch, no barriers).
// ---------------------------------------------------------------------------
__global__ __launch_bounds__(512) void gemm8_qkv(const bf16_t* __restrict__ A,
                                                 const bf16_t* __restrict__ Bq,
                                                 const bf16_t* __restrict__ Bk,
                                                 const bf16_t* __restrict__ Bv,
                                                 bf16_t* __restrict__ Qw,
                                                 bf16_t* __restrict__ Kw,
                                                 bf16_t* __restrict__ Vw,
                                                 const float* __restrict__ fcos,
                                                 const float* __restrict__ fsin,
                                                 const float* __restrict__ woS,
                                                 bf16_t* __restrict__ woD,
                                                 int wo_n8) {
  __shared__ __align__(16) bf16_t As[32768];  // 2 buf x 2 half x 128x64
  __shared__ __align__(16) bf16_t Bs[32768];

  if (blockIdx.x >= 24) {
    // converter path: 64 blocks x 512 threads, vec8 grid-stride over wo.
    const int cb     = (blockIdx.x - 24) + 8 * blockIdx.y;  // 0..63
    const int tid    = cb * 512 + threadIdx.x;
    const int stride = 64 * 512;
    for (int i = tid; i < wo_n8; i += stride) {
      const float* p = woS + (size_t)i * 8;
      f32x4 a = *(const f32x4*)p, b = *(const f32x4*)(p + 4);
      bf16x8 r;
#pragma unroll
      for (int q = 0; q < 4; ++q) { r[q] = (bf16_t)a[q]; r[q + 4] = (bf16_t)b[q]; }
      *(bf16x8*)(woD + (size_t)i * 8) = r;
    }
    return;
  }

  const G8Idx g = g8_idx();
  const int tm = blockIdx.y * 256;
  const int tn = blockIdx.x * 256;
  const int K  = DIM;

  const int region = (tn >= DIM + KVDIM) ? 2 : (tn >= DIM ? 1 : 0);
  const bf16_t* Bsel;
  int bn;
  if (region == 0)      { Bsel = Bq; bn = tn; }
  else if (region == 1) { Bsel = Bk; bn = tn - DIM; }
  else                  { Bsel = Bv; bn = tn - DIM - KVDIM; }

  const bf16_t* gAt = A + (size_t)(tm + g.rowl) * K + g.colS;
  const bf16_t* gBt = Bsel + (size_t)(bn + g.rowl) * K + g.colS;
  bf16_t* lAt = As + g.rowl * 64 + g.colL;
  bf16_t* lBt = Bs + g.rowl * 64 + g.colL;
  const bf16_t* rA = As + g.wr * 8192 + g.l16 * 64;
  const bf16_t* rB = Bs + (g.wc >> 1) * 8192 + ((g.wc & 1) * 64 + g.l16) * 64;

  f32x4 acc[2][4][2][2] = {};
  gemm256_loop(gAt, gBt, lAt, lBt, rA, rB, g.swz0, g.swz1, K, K, acc);

  // epilogue. C/D frag layout: col = l16, row = quad*4 + r.
  if (region == 2) {
    // V: transposed store Vw[d][s]
#pragma unroll
    for (int mh = 0; mh < 2; ++mh)
#pragma unroll
      for (int mt = 0; mt < 4; ++mt)
#pragma unroll
        for (int nh = 0; nh < 2; ++nh)
#pragma unroll
          for (int n2 = 0; n2 < 2; ++n2) {
            const int row = tm + g.wr * 128 + mh * 64 + mt * 16 + g.quad * 4;
            const int col = bn + g.wc * 64 + nh * 32 + n2 * 16 + g.l16;
#pragma unroll
            for (int r = 0; r < 4; ++r)
              Vw[(size_t)col * SEQ + row + r] = (bf16_t)acc[mh][mt][nh][n2][r];
          }
  } else {
    // Q or K: RoPE via lane^1 partner exchange; Q additionally scaled.
    const float sc   = (region == 0) ? ATTN_SCALE : 1.0f;
    const bool  even = ((g.l16 & 1) == 0);
#pragma unroll
    for (int mh = 0; mh < 2; ++mh)
#pragma unroll
      for (int mt = 0; mt < 4; ++mt)
#pragma unroll
        for (int nh = 0; nh < 2; ++nh)
#pragma unroll
          for (int n2 = 0; n2 < 2; ++n2) {
            const int col = bn + g.wc * 64 + nh * 32 + n2 * 16 + g.l16;
            const int j   = (col & 127) >> 1;
#pragma unroll
            for (int r = 0; r < 4; ++r) {
              const int row = tm + g.wr * 128 + mh * 64 + mt * 16 + g.quad * 4 + r;
              const float v  = acc[mh][mt][nh][n2][r];
              const float p  = __shfl_xor(v, 1, 64);
              const float c  = fcos[row * 64 + j];
              const float sn = fsin[row * 64 + j];
              const float o  = sc * (even ? (v * c - p * sn) : (p * sn + v * c));
              if (region == 0) Qw[(size_t)row * DIM + col]   = (bf16_t)o;
              else             Kw[(size_t)row * KVDIM + col] = (bf16_t)o;
            }
          }
  }
}

// ---------------------------------------------------------------------------
// R9-proven single-pass W_o GEMM, 256x128 tile, BK=64, 8 waves (2Mx4N of 32
// cols), 512 threads, 96 KiB LDS, grid (N/128, M/256) = 256 blocks = 1/CU.
// 2 phases/K-tile, counted vmcnt(2).
// ---------------------------------------------------------------------------
__global__ __launch_bounds__(512) void gemm8_no(const bf16_t* __restrict__ A,
                                                const bf16_t* __restrict__ B,
                                                float* __restrict__ C,
                                                int M, int N, int K) {
  __shared__ __align__(16) bf16_t As[32768];  // 2 buf x 2 half x 128x64 (64 KiB)
  __shared__ __align__(16) bf16_t Bs[16384];  // 2 buf x 128x64 (32 KiB)

  const G8Idx g = g8_idx();
  const int tm = blockIdx.y * 256;
  const int tn = blockIdx.x * 128;
  const int NT = K >> 6;

  const bf16_t* gAt = A + (size_t)(tm + g.rowl) * K + g.colS;
  const bf16_t* gBt = B + (size_t)(tn + g.rowl) * K + g.colS;
  bf16_t* lAt = As + g.rowl * 64 + g.colL;
  bf16_t* lBt = Bs + g.rowl * 64 + g.colL;
  const bf16_t* rA = As + g.wr * 8192 + g.l16 * 64;
  const bf16_t* rB = Bs + (g.wc * 32 + g.l16) * 64;

  f32x4 acc[2][4][2] = {};
  bf16x8 af[4][2];
  bf16x8 bfr[2][2];  // n2 x ks

#define N1_STA(b, h, kt) do { \
    gld_lds16(gAt + (size_t)((h) * 128) * K + (size_t)(kt) * 64, \
              lAt + (b) * 16384 + (h) * 8192); \
    gld_lds16(gAt + (size_t)((h) * 128 + 64) * K + (size_t)(kt) * 64, \
              lAt + (b) * 16384 + (h) * 8192 + 4096); \
  } while (0)
#define N1_STB(b, kt) do { \
    gld_lds16(gBt + (size_t)(kt) * 64, lBt + (b) * 8192); \
    gld_lds16(gBt + (size_t)64 * K + (size_t)(kt) * 64, lBt + (b) * 8192 + 4096); \
  } while (0)
#define N1_RDA(b, mh) do { \
    _Pragma("unroll") \
    for (int mt = 0; mt < 4; ++mt) { \
      const bf16_t* p_ = rA + (b) * 16384 + ((mh) * 64 + mt * 16) * 64; \
      af[mt][0] = *(const bf16x8*)(p_ + g.swz0); \
      af[mt][1] = *(const bf16x8*)(p_ + g.swz1); \
    } \
  } while (0)
#define N1_RDB(b) do { \
    _Pragma("unroll") \
    for (int n2 = 0; n2 < 2; ++n2) { \
      const bf16_t* p_ = rB + (b) * 8192 + (n2 * 16) * 64; \
      bfr[n2][0] = *(const bf16x8*)(p_ + g.swz0); \
      bfr[n2][1] = *(const bf16x8*)(p_ + g.swz1); \
    } \
  } while (0)
#define N1_MM(mh) do { \
    _Pragma("unroll") \
    for (int mt = 0; mt < 4; ++mt) \
      _Pragma("unroll") \
      for (int n2 = 0; n2 < 2; ++n2) \
        _Pragma("unroll") \
        for (int ks = 0; ks < 2; ++ks) \
          acc[mh][mt][n2] = __builtin_amdgcn_mfma_f32_16x16x32_bf16( \
              af[mt][ks], bfr[n2][ks], acc[mh][mt][n2], 0, 0, 0); \
  } while (0)
#define N1_BAR()   __builtin_amdgcn_s_barrier()
#define N1_SB()    __builtin_amdgcn_sched_barrier(0)
#define N1_LGKM0() asm volatile("s_waitcnt lgkmcnt(0)" ::: "memory")

  // prologue: tile0 A+B, tile1 B (steady-state queue shape)
  N1_STA(0, 0, 0); N1_STA(0, 1, 0); N1_STB(0, 0); N1_STB(1, 1);
  asm volatile("s_waitcnt vmcnt(2)" ::: "memory");  // tile0 landed; t1 B in flight
  N1_BAR(); N1_SB();

  for (int t = 0; t < NT; ++t) {
    const int  b  = t & 1, ob = b ^ 1;
    const bool sA = (t + 1 < NT);
    const bool sB = (t + 2 < NT);

    // ---- phase 1: mh0 (12 ds_reads)
    N1_RDA(b, 0);
    N1_RDB(b);
    if (sA) { N1_STA(ob, 0, t + 1); N1_STA(ob, 1, t + 1); }
    asm volatile("s_waitcnt lgkmcnt(8)" ::: "memory");
    N1_BAR(); N1_LGKM0(); N1_SB();
    __builtin_amdgcn_s_setprio(1); N1_MM(0); __builtin_amdgcn_s_setprio(0);
    N1_BAR(); N1_SB();

    // ---- phase 2: mh1 (+ counted vmcnt, never 0 in steady state)
    N1_RDA(b, 1);
    if (sB) N1_STB(b, t + 2);
    N1_BAR(); N1_LGKM0(); N1_SB();
    __builtin_amdgcn_s_setprio(1); N1_MM(1); __builtin_amdgcn_s_setprio(0);
    if (sB) { asm volatile("s_waitcnt vmcnt(2)" ::: "memory"); }
    else    { asm volatile("s_waitcnt vmcnt(0)" ::: "memory"); }
    N1_BAR(); N1_SB();
  }

#undef N1_STA
#undef N1_STB
#undef N1_RDA
#undef N1_RDB
#undef N1_MM
#undef N1_BAR
#undef N1_SB
#undef N1_LGKM0

  // epilogue: fp32 C
#pragma unroll
  for (int mh = 0; mh < 2; ++mh)
#pragma unroll
    for (int mt = 0; mt < 4; ++mt)
#pragma unroll
      for (int n2 = 0; n2 < 2; ++n2) {
        const int col = tn + g.wc * 32 + n2 * 16 + g.l16;
#pragma unroll
        for (int r = 0; r < 4; ++r) {
          const int row = tm + g.wr * 128 + mh * 64 + mt * 16 + g.quad * 4 + r;
          C[(size_t)row * N + col] = acc[mh][mt][n2][r];
        }
      }
}

// ---------------------------------------------------------------------------
// shared GEMM main loop (R5, 128x128, kept for fallback tiers)
// ---------------------------------------------------------------------------
template <typename TB>
__device__ __forceinline__ void gemm_mainloop(const bf16_t* gA, const TB* gB, int K,
                                              bf16_t* As, bf16_t* Bs,
                                              bf16_t* lA, bf16_t* lB,
                                              int wr, int wc, int l16, int quad,
                                              f32x4 (&acc)[4][4]) {
  for (int kt = 0; kt < K; kt += 64) {
#pragma unroll
    for (int i = 0; i < 4; ++i)
      gld_lds16(gA + (size_t)i * 32 * K + kt, lA + i * 2048);
    if constexpr (sizeof(TB) == 2) {
#pragma unroll
      for (int i = 0; i < 4; ++i)
        gld_lds16((const bf16_t*)gB + (size_t)i * 32 * K + kt, lB + i * 2048);
    } else {
      bf16x8 rb[4];
#pragma unroll
      for (int i = 0; i < 4; ++i) rb[i] = load8(gB + (size_t)i * 32 * K + kt);
#pragma unroll
      for (int i = 0; i < 4; ++i) *(bf16x8*)(lB + i * 2048) = rb[i];
    }
    __syncthreads();

#pragma unroll
    for (int ks = 0; ks < 2; ++ks) {
      bf16x8 af[4], bfr[4];
#pragma unroll
      for (int mt = 0; mt < 4; ++mt)
        af[mt] = *(const bf16x8*)&As[(wr * 64 + mt * 16 + l16) * 64 + ks * 32 + quad * 8];
#pragma unroll
      for (int nt = 0; nt < 4; ++nt)
        bfr[nt] = *(const bf16x8*)&Bs[(wc * 64 + nt * 16 + l16) * 64 + ks * 32 + quad * 8];
#pragma unroll
      for (int mt = 0; mt < 4; ++mt)
#pragma unroll
        for (int nt = 0; nt < 4; ++nt)
          acc[mt][nt] = __builtin_amdgcn_mfma_f32_16x16x32_bf16(af[mt], bfr[nt],
                                                                acc[mt][nt], 0, 0, 0);
    }
    __syncthreads();
  }
}

// ---------------------------------------------------------------------------
// R5 fused QKV (128x128) — fallback tier B (fp32 weights path)
// ---------------------------------------------------------------------------
template <typename TB>
__global__ __launch_bounds__(256) void gemm_qkv(const bf16_t* __restrict__ A,
                                                const TB* __restrict__ Bq,
                                                const TB* __restrict__ Bk,
                                                const TB* __restrict__ Bv,
                                                bf16_t* __restrict__ Qw,
                                                bf16_t* __restrict__ Kw,
                                                bf16_t* __restrict__ Vw,
                                                const float* __restrict__ fcos,
                                                const float* __restrict__ fsin) {
  __shared__ __align__(16) bf16_t As[128 * 64];
  __shared__ __align__(16) bf16_t Bs[128 * 64];

  const int t    = threadIdx.x;
  const int w    = t >> 6;
  const int lane = t & 63;
  const int wr   = w >> 1;
  const int wc   = w & 1;
  const int l16  = lane & 15;
  const int quad = lane >> 4;
  const int tm   = blockIdx.y * 128;
  const int tn   = blockIdx.x * 128;
  const int srow = lane >> 3;
  const int scol = (lane & 7) * 8;
  const int K    = DIM;

  const int region = (tn >= DIM + KVDIM) ? 2 : (tn >= DIM ? 1 : 0);
  const TB* Bsel;
  int bn;
  if (region == 0)      { Bsel = Bq; bn = tn; }
  else if (region == 1) { Bsel = Bk; bn = tn - DIM; }
  else                  { Bsel = Bv; bn = tn - DIM - KVDIM; }

  const bf16_t* gA = A + (size_t)(tm + w * 8 + srow) * K + scol;
  const TB*     gB = Bsel + (size_t)(bn + w * 8 + srow) * K + scol;
  bf16_t* lA = &As[(w * 8 + srow) * 64 + scol];
  bf16_t* lB = &Bs[(w * 8 + srow) * 64 + scol];

  f32x4 acc[4][4] = {};
  gemm_mainloop<TB>(gA, gB, K, As, Bs, lA, lB, wr, wc, l16, quad, acc);

  if (region == 2) {
#pragma unroll
    for (int mt = 0; mt < 4; ++mt)
#pragma unroll
      for (int nt = 0; nt < 4; ++nt) {
        const int row = tm + wr * 64 + mt * 16 + quad * 4;
        const int col = bn + wc * 64 + nt * 16 + l16;
#pragma unroll
        for (int r = 0; r < 4; ++r)
          Vw[(size_t)col * SEQ + row + r] = (bf16_t)acc[mt][nt][r];
      }
  } else {
    const float sc = (region == 0) ? ATTN_SCALE : 1.0f;
    const bool even = ((l16 & 1) == 0);
#pragma unroll
    for (int mt = 0; mt < 4; ++mt)
#pragma unroll
      for (int nt = 0; nt < 4; ++nt) {
        const int col = bn + wc * 64 + nt * 16 + l16;
        const int j   = (col & 127) >> 1;
#pragma unroll
        for (int r = 0; r < 4; ++r) {
          const int row = tm + wr * 64 + mt * 16 + quad * 4 + r;
          const float v = acc[mt][nt][r];
          const float p = __shfl_xor(v, 1, 64);
          const float c  = fcos[row * 64 + j];
          const float sn = fsin[row * 64 + j];
          const float o  = sc * (even ? (v * c - p * sn) : (p * sn + v * c));
          if (region == 0) Qw[(size_t)row * DIM + col]   = (bf16_t)o;
          else             Kw[(size_t)row * KVDIM + col] = (bf16_t)o;
        }
      }
  }
}

// ---------------------------------------------------------------------------
// Plain GEMM (128x128) — fallback tier B
// ---------------------------------------------------------------------------
template <typename TB, typename TC>
__global__ __launch_bounds__(256) void gemm_lds(const bf16_t* __restrict__ A,
                                                const TB* __restrict__ B,
                                                TC* __restrict__ C,
                                                int M, int N, int K) {
  __shared__ __align__(16) bf16_t As[128 * 64];
  __shared__ __align__(16) bf16_t Bs[128 * 64];

  const int t    = threadIdx.x;
  const int w    = t >> 6;
  const int lane = t & 63;
  const int wr   = w >> 1;
  const int wc   = w & 1;
  const int l16  = lane & 15;
  const int quad = lane >> 4;
  const int tm   = blockIdx.y * 128;
  const int tn   = blockIdx.x * 128;
  const int srow = lane >> 3;
  const int scol = (lane & 7) * 8;

  const bf16_t* gA = A + (size_t)(tm + w * 8 + srow) * K + scol;
  const TB*     gB = B + (size_t)(tn + w * 8 + srow) * K + scol;
  bf16_t* lA = &As[(w * 8 + srow) * 64 + scol];
  bf16_t* lB = &Bs[(w * 8 + srow) * 64 + scol];

  f32x4 acc[4][4] = {};
  gemm_mainloop<TB>(gA, gB, K, As, Bs, lA, lB, wr, wc, l16, quad, acc);

#pragma unroll
  for (int mt = 0; mt < 4; ++mt)
#pragma unroll
    for (int nt = 0; nt < 4; ++nt)
#pragma unroll
      for (int r = 0; r < 4; ++r) {
        const int row = tm + wr * 64 + mt * 16 + quad * 4 + r;
        const int col = tn + wc * 64 + nt * 16 + l16;
        C[(size_t)row * N + col] = (TC)acc[mt][nt][r];
      }
}

// ---------------------------------------------------------------------------
// R3-style register-staging GEMM (fallback tier C)
// ---------------------------------------------------------------------------
template <typename TA, typename TB, typename TC, bool TRANSPOSE_C>
__global__ __launch_bounds__(256) void gemm_reg(const TA* __restrict__ A,
                                                const TB* __restrict__ B,
                                                TC* __restrict__ C,
                                                int M, int N, int K) {
  __shared__ __align__(16) bf16_t As[128 * 64];
  __shared__ __align__(16) bf16_t Bs[128 * 64];

  const int t    = threadIdx.x;
  const int w    = t >> 6;
  const int lane = t & 63;
  const int wr   = w >> 1;
  const int wc   = w & 1;
  const int l16  = lane & 15;
  const int quad = lane >> 4;
  const int tm   = blockIdx.y * 128;
  const int tn   = blockIdx.x * 128;
  const int srow = lane >> 3;
  const int scol = (lane & 7) * 8;

  const TA* gA = A + (size_t)(tm + w * 8 + srow) * K + scol;
  const TB* gB = B + (size_t)(tn + w * 8 + srow) * K + scol;
  bf16_t* lA = &As[(w * 8 + srow) * 64 + scol];
  bf16_t* lB = &Bs[(w * 8 + srow) * 64 + scol];

  f32x4 acc[4][4] = {};

  for (int kt = 0; kt < K; kt += 64) {
    bf16x8 ra[4], rb[4];
#pragma unroll
    for (int i = 0; i < 4; ++i) ra[i] = load8(gA + (size_t)i * 32 * K + kt);
#pragma unroll
    for (int i = 0; i < 4; ++i) rb[i] = load8(gB + (size_t)i * 32 * K + kt);
#pragma unroll
    for (int i = 0; i < 4; ++i) *(bf16x8*)(lA + i * 2048) = ra[i];
#pragma unroll
    for (int i = 0; i < 4; ++i) *(bf16x8*)(lB + i * 2048) = rb[i];
    __syncthreads();

#pragma unroll
    for (int ks = 0; ks < 2; ++ks) {
      bf16x8 af[4], bfr[4];
#pragma unroll
      for (int mt = 0; mt < 4; ++mt)
        af[mt] = *(const bf16x8*)&As[(wr * 64 + mt * 16 + l16) * 64 + ks * 32 + quad * 8];
#pragma unroll
      for (int nt = 0; nt < 4; ++nt)
        bfr[nt] = *(const bf16x8*)&Bs[(wc * 64 + nt * 16 + l16) * 64 + ks * 32 + quad * 8];
#pragma unroll
      for (int mt = 0; mt < 4; ++mt)
#pragma unroll
        for (int nt = 0; nt < 4; ++nt)
          acc[mt][nt] = __builtin_amdgcn_mfma_f32_16x16x32_bf16(af[mt], bfr[nt],
                                                                acc[mt][nt], 0, 0, 0);
    }
    __syncthreads();
  }

  if (!TRANSPOSE_C) {
#pragma unroll
    for (int mt = 0; mt < 4; ++mt)
#pragma unroll
      for (int nt = 0; nt < 4; ++nt)
#pragma unroll
        for (int r = 0; r < 4; ++r) {
          const int row = tm + wr * 64 + mt * 16 + quad * 4 + r;
          const int col = tn + wc * 64 + nt * 16 + l16;
          C[(size_t)row * N + col] = (TC)acc[mt][nt][r];
        }
  } else {
#pragma unroll
    for (int mt = 0; mt < 4; ++mt)
#pragma unroll
      for (int nt = 0; nt < 4; ++nt) {
        const int row = tm + wr * 64 + mt * 16 + quad * 4;
        const int col = tn + wc * 64 + nt * 16 + l16;
#pragma unroll
        for (int r = 0; r < 4; ++r)
          C[(size_t)col * M + row + r] = (TC)acc[mt][nt][r];
      }
  }
}

// ---------------------------------------------------------------------------
// RoPE in place on bf16 T[s][h*128+d] (fallback tiers), post-scale `sc`.
// ---------------------------------------------------------------------------
template <int NH_T>
__global__ __launch_bounds__(256) void rope_kernel(bf16_t* __restrict__ T,
                                                   const float* __restrict__ cosb,
                                                   const float* __restrict__ sinb,
                                                   float sc) {
  const int idx = blockIdx.x * 256 + threadIdx.x;
  if (idx >= SEQ * NH_T * 64) return;
  const int j = idx & 63;
  const int h = (idx >> 6) & (NH_T - 1);
  const int s = idx >> 6 >> (NH_T == 32 ? 5 : 3);
  const float c  = cosb[s * 64 + j];
  const float sn = sinb[s * 64 + j];
  const size_t o = (size_t)s * (NH_T * HD) + h * HD + 2 * j;
  const float re = (float)T[o];
  const float im = (float)T[o + 1];
  T[o]     = (bf16_t)(sc * (re * c - im * sn));
  T[o + 1] = (bf16_t)(sc * (re * sn + im * c));
}

// ---------------------------------------------------------------------------
// Flash attention (causal, GQA 4:1). Q pre-scaled by 1/sqrt(d).
// R8 fused-pair structure: one k-loop per block; paired Q-tiles (qtL,
// qtH=31-qtL) share K/V staging; double-buffered Ks/Vs, T14, T5.
// ---------------------------------------------------------------------------
__global__ __launch_bounds__(256, 2) void flash_attn(const bf16_t* __restrict__ Q,
                                                     const bf16_t* __restrict__ Kc,
                                                     const bf16_t* __restrict__ Vt,
                                                     bf16_t* __restrict__ O) {
  __shared__ __align__(16) bf16_t Ks[2 * 64 * 128];
  __shared__ __align__(16) bf16_t Vs[2 * 128 * 64];
  __shared__ __align__(16) bf16_t Ps[4 * 16 * 72];

  const int t    = threadIdx.x;
  const int w    = t >> 6;
  const int lane = t & 63;
  const int l16  = lane & 15;
  const int quad = lane >> 4;
  const int h    = blockIdx.x;
  const int hk   = h >> 2;
  const int krow = lane >> 4, kcol = (lane & 15) * 8;
  const int vrow = lane >> 3, vcol = (lane & 7) * 8;
  bf16_t* Pw = &Ps[w * 1152];

#define F_LOAD(KT) do { \
    _Pragma("unroll") \
    for (int i = 0; i < 4; ++i) \
      rk[i] = *(const bf16x8*)(Kc + (size_t)((KT) * 64 + (i * 4 + w) * 4 + krow) * KVDIM \
                               + hk * HD + kcol); \
    _Pragma("unroll") \
    for (int i = 0; i < 4; ++i) \
      rv[i] = *(const bf16x8*)(Vt + (size_t)(hk * HD + (i * 4 + w) * 8 + vrow) * SEQ \
                               + (KT) * 64 + vcol); \
  } while (0)
#define F_STORE(KB, VB) do { \
    _Pragma("unroll") \
    for (int i = 0; i < 4; ++i) { \
      const int r = (i * 4 + w) * 4 + krow; \
      *(bf16x8*)&(KB)[r * 128 + ((l16 ^ (r & 15)) * 8)] = rk[i]; \
    } \
    _Pragma("unroll") \
    for (int i = 0; i < 4; ++i) { \
      const int r = (i * 4 + w) * 8 + vrow; \
      *(bf16x8*)&(VB)[r * 64 + (((lane & 7) ^ (r & 7)) * 8)] = rv[i]; \
    } \
  } while (0)

// one half's QK^T -> masked exp -> P staging -> PV accumulate for tile kt
#define F_HALF(QA, OA, LR, QT) do { \
    f32x4 s_acc[4]; \
    __builtin_amdgcn_s_setprio(1); \
    _Pragma("unroll") \
    for (int nt = 0; nt < 4; ++nt) { \
      f32x4 a = {}; \
      _Pragma("unroll") \
      for (int ks = 0; ks < 4; ++ks) { \
        bf16x8 kb = *(const bf16x8*)&KsC[(nt * 16 + l16) * 128 + (((ks * 4 + quad) ^ l16) * 8)]; \
        a = __builtin_amdgcn_mfma_f32_16x16x32_bf16((QA)[ks], kb, a, 0, 0, 0); \
      } \
      s_acc[nt] = a; \
    } \
    __builtin_amdgcn_s_setprio(0); \
    const bool diag_ = (kt == (QT)); \
    _Pragma("unroll") \
    for (int r = 0; r < 4; ++r) { \
      const int grow_rel = w * 16 + quad * 4 + r; \
      _Pragma("unroll") \
      for (int nt = 0; nt < 4; ++nt) { \
        float p = __expf(fminf(s_acc[nt][r], 30.f)); \
        if (diag_ && (nt * 16 + l16) > grow_rel) p = 0.f; \
        (LR)[r] += p; \
        Pw[(quad * 4 + r) * 72 + nt * 16 + l16] = (bf16_t)p; \
      } \
    } \
    bf16x8 pa[2]; \
    _Pragma("unroll") \
    for (int ks = 0; ks < 2; ++ks) \
      pa[ks] = *(const bf16x8*)&Pw[l16 * 72 + ks * 32 + quad * 8]; \
    __builtin_amdgcn_s_setprio(1); \
    _Pragma("unroll") \
    for (int nt8 = 0; nt8 < 8; ++nt8) \
      _Pragma("unroll") \
      for (int ks = 0; ks < 2; ++ks) { \
        bf16x8 vb = *(const bf16x8*)&VsC[(nt8 * 16 + l16) * 64 \
                                         + (((ks * 4 + quad) ^ (l16 & 7)) * 8)]; \
        (OA)[nt8] = __builtin_amdgcn_mfma_f32_16x16x32_bf16(pa[ks], vb, (OA)[nt8], 0, 0, 0); \
      } \
    __builtin_amdgcn_s_setprio(0); \
  } while (0)

  const int qtL = blockIdx.y;       // 0..15
  const int qtH = 31 - qtL;         // 16..31

  bf16x8 qaL[4], qaH[4];
  {
    const int qrowL = qtL * 64 + w * 16 + l16;
    const int qrowH = qtH * 64 + w * 16 + l16;
#pragma unroll
    for (int ks = 0; ks < 4; ++ks) {
      qaL[ks] = *(const bf16x8*)&Q[(size_t)qrowL * DIM + h * HD + ks * 32 + quad * 8];
      qaH[ks] = *(const bf16x8*)&Q[(size_t)qrowH * DIM + h * HD + ks * 32 + quad * 8];
    }
  }

  f32x4 oaL[8] = {}, oaH[8] = {};
  float lrL[4] = {0.f, 0.f, 0.f, 0.f};
  float lrH[4] = {0.f, 0.f, 0.f, 0.f};

  bf16x8 rk[4], rv[4];
  F_LOAD(0);
  F_STORE(Ks, Vs);  // buf0
  __syncthreads();

  for (int kt = 0; kt <= qtH; ++kt) {
    const int cur = kt & 1;
    const bf16_t* KsC = Ks + cur * 8192;
    const bf16_t* VsC = Vs + cur * 8192;
    bf16_t* KsN = Ks + (cur ^ 1) * 8192;
    bf16_t* VsN = Vs + (cur ^ 1) * 8192;
    const bool pf = (kt < qtH);

    if (pf) F_LOAD(kt + 1);  // issue early; lands during compute (T14)

    F_HALF(qaH, oaH, lrH, qtH);
    if (kt <= qtL) F_HALF(qaL, oaL, lrL, qtL);

    if (pf) F_STORE(KsN, VsN);  // write-late into the other buffer
    __syncthreads();
  }

  // epilogue: both halves
#pragma unroll
  for (int r = 0; r < 4; ++r) {
    float rsH = lrH[r], rsL = lrL[r];
#pragma unroll
    for (int off = 1; off < 16; off <<= 1) {
      rsH += __shfl_xor(rsH, off, 64);
      rsL += __shfl_xor(rsL, off, 64);
    }
    lrH[r] = 1.0f / rsH;
    lrL[r] = 1.0f / rsL;
  }
#pragma unroll
  for (int nt8 = 0; nt8 < 8; ++nt8)
#pragma unroll
    for (int r = 0; r < 4; ++r) {
      const int rowH = qtH * 64 + w * 16 + quad * 4 + r;
      const int rowL = qtL * 64 + w * 16 + quad * 4 + r;
      O[(size_t)rowH * DIM + h * HD + nt8 * 16 + l16] = (bf16_t)(oaH[nt8][r] * lrH[r]);
      O[(size_t)rowL * DIM + h * HD + nt8 * 16 + l16] = (bf16_t)(oaL[nt8][r] * lrL[r]);
    }
#undef F_LOAD
#undef F_STORE
#undef F_HALF
}

// ---------------------------------------------------------------------------
extern "C" void kernel_launch(void* const* d_in, const int* in_sizes, int n_in,
                              void* d_out, int out_size, void* d_ws, size_t ws_size,
                              hipStream_t stream) {
  const float* x    = (const float*)d_in[0];
  const float* wq   = (const float*)d_in[1];
  const float* wk   = (const float*)d_in[2];
  const float* wv   = (const float*)d_in[3];
  const float* wo   = (const float*)d_in[4];
  const float* fcos = (const float*)d_in[7];
  const float* fsin = (const float*)d_in[8];
  float* out = (float*)d_out;

  bf16_t* Qw = (bf16_t*)d_out;  // Q scratch in d_out, dead before final GEMM
  bf16_t* ws = (bf16_t*)d_ws;

  const size_t N_X  = (size_t)SEQ * DIM;
  const size_t N_WQ = (size_t)DIM * DIM;
  const size_t N_WK = (size_t)KVDIM * DIM;
  const size_t N_KV = (size_t)SEQ * KVDIM;

  const size_t NEED_A = (N_X + N_WQ + 2 * N_WK + N_WQ + 2 * N_KV + N_X) * 2;  // 120 MiB
  const size_t NEED_B = (N_X + 2 * N_KV + N_X) * 2;                           // 40 MiB

  const dim3 blk(256);

  if (ws_size >= NEED_A) {
    bf16_t* xb  = ws;
    bf16_t* wqb = xb + N_X;
    bf16_t* wkb = wqb + N_WQ;
    bf16_t* wvb = wkb + N_WK;
    bf16_t* wob = wvb + N_WK;
    bf16_t* Kw  = wob + N_WQ;
    bf16_t* Vw  = Kw + N_KV;
    bf16_t* Aw  = Vw + N_KV;

    // cvt: x, wq, wk, wv only — wo is converted by qkv's idle-CU blocks.
    const int total8 = (int)((N_X + N_WQ + 2 * N_WK) / 8);
    to_bf16_multi<<<2048, blk, 0, stream>>>(
        CvtJob{x, xb, (int)(N_X / 8)}, CvtJob{wq, wqb, (int)(N_WQ / 8)},
        CvtJob{wk, wkb, (int)(N_WK / 8)}, CvtJob{wv, wvb, (int)(N_WK / 8)},
        CvtJob{wo, wob, 0}, total8);

    // 4-phase 256x256 QKV (192 GEMM blocks) + 64 wo-converter blocks = 256.
    gemm8_qkv<<<dim3(32, SEQ / 256), dim3(512), 0, stream>>>(
        xb, wqb, wkb, wvb, Qw, Kw, Vw, fcos, fsin,
        wo, wob, (int)(N_WQ / 8));
    flash_attn<<<dim3(NHEADS, 16), blk, 0, stream>>>(Qw, Kw, Vw, Aw);

    // R9 2-phase W_o: 256x128 tiles, grid 32x8 = 256 blocks.
    gemm8_no<<<dim3(DIM / 128, SEQ / 256), dim3(512), 0, stream>>>(
        Aw, wob, out, SEQ, DIM, DIM);
  } else if (ws_size >= NEED_B) {
    bf16_t* xb = ws;
    bf16_t* Kw = xb + N_X;
    bf16_t* Vw = Kw + N_KV;
    bf16_t* Aw = Vw + N_KV;

    const int total8 = (int)(N_X / 8);
    to_bf16_multi<<<2048, blk, 0, stream>>>(
        CvtJob{x, xb, total8}, CvtJob{x, xb, 0}, CvtJob{x, xb, 0},
        CvtJob{x, xb, 0}, CvtJob{x, xb, 0}, total8);

    gemm_qkv<float><<<dim3(48, SEQ / 128), blk, 0, stream>>>(
        xb, wq, wk, wv, Qw, Kw, Vw, fcos, fsin);
    flash_attn<<<dim3(NHEADS, 16), blk, 0, stream>>>(Qw, Kw, Vw, Aw);
    gemm_lds<float, float>
        <<<dim3(DIM / 128, SEQ / 128), blk, 0, stream>>>(Aw, wo, out, SEQ, DIM, DIM);
  } else {
    // tier C fallback (R3-proven, 24 MiB ws)
    bf16_t* Kw = ws;
    bf16_t* Vw = Kw + N_KV;
    bf16_t* Aw = Vw + N_KV;

    gemm_reg<float, float, bf16_t, false>
        <<<dim3(DIM / 128, SEQ / 128), blk, 0, stream>>>(x, wq, Qw, SEQ, DIM, DIM);
    gemm_reg<float, float, bf16_t, false>
        <<<dim3(KVDIM / 128, SEQ / 128), blk, 0, stream>>>(x, wk, Kw, SEQ, KVDIM, DIM);
    gemm_reg<float, float, bf16_t, true>
        <<<dim3(KVDIM / 128, SEQ / 128), blk, 0, stream>>>(x, wv, Vw, SEQ, KVDIM, DIM);
    rope_kernel<NHEADS><<<SEQ * NHEADS * 64 / 256, blk, 0, stream>>>(Qw, fcos, fsin, ATTN_SCALE);
    rope_kernel<NKV><<<SEQ * NKV * 64 / 256, blk, 0, stream>>>(Kw, fcos, fsin, 1.0f);
    flash_attn<<<dim3(NHEADS, 16), blk, 0, stream>>>(Qw, Kw, Vw, Aw);
    gemm_reg<bf16_t, float, float, false>
        <<<dim3(DIM / 128, SEQ / 128), blk, 0, stream>>>(Aw, wo, out, SEQ, DIM, DIM);
  }
}